// Round 7
// baseline (238.281 us; speedup 1.0000x reference)
//
#include <hip/hip_runtime.h>

#define N_NODES 100000
#define E_EDGES 1600000
#define C 128
#define BSHIFT 10
#define NBKT 98       // ceil(N/1024)
#define CAP 18432     // bucket capacity; mean 16384, sigma ~127 -> +16 sigma

#define PA_BLOCKS 782     // passA role: 2048 edges per 512-thr block
#define PACK_BLOCKS 8     // pack role: 4096 frag-items
#define CVT_BLOCKS 3125   // cvt role: 1.6M uint4

typedef __attribute__((ext_vector_type(8))) short short8;   // 8 bf16 (4 VGPRs)
typedef __attribute__((ext_vector_type(4))) float f32x4;    // MFMA acc

__device__ __forceinline__ unsigned short f2bf(float f) {  // RNE fp32->bf16
  unsigned int b = __float_as_uint(f);
  return (unsigned short)((b + 0x7fffu + ((b >> 16) & 1u)) >> 16);
}
__device__ __forceinline__ float bflo(unsigned int v) {
  return __uint_as_float(v << 16);
}
__device__ __forceinline__ float bfhi(unsigned int v) {
  return __uint_as_float(v & 0xffff0000u);
}

// ---------------------------------------------------------------------------
// mega: passA (multisplit by dst>>10) + W-pack + x->bf16 cvt, one dispatch.
// The three roles are independent; running them as one grid overlaps their
// memory streams and deletes two launch gaps.
// ---------------------------------------------------------------------------
__global__ __launch_bounds__(512) void mega_kernel(
    const float* __restrict__ x, const int* __restrict__ erow,
    const int* __restrict__ ecol, const float* __restrict__ W_l,
    const float* __restrict__ W_r, ushort* __restrict__ xh,
    ushort* __restrict__ Bp, int* __restrict__ bcnt, int* __restrict__ pairs) {
  __shared__ int cnt[NBKT], pos[NBKT], loff[NBKT], total;
  __shared__ int lbuf[2048];
  __shared__ int gaddr[2048];
  int bid = blockIdx.x;
  int tid = threadIdx.x;

  if (bid < PA_BLOCKS) {
    // ---- passA: LDS 98-way split, one global atomic per bucket per block,
    //      bucket-ordered ~84 B runs into fixed-CAP regions of `pairs`.
    for (int b = tid; b < NBKT; b += 512) cnt[b] = 0;
    __syncthreads();

    int idx = bid * 512 + tid;  // int4 index: edges [4*idx, 4*idx+4)
    bool ok = (idx < E_EDGES / 4);
    int4 r, c;
    int bk[4], rk[4];
    if (ok) {
      r = ((const int4*)erow)[idx];
      c = ((const int4*)ecol)[idx];
      bk[0] = r.x >> BSHIFT; rk[0] = atomicAdd(&cnt[bk[0]], 1);
      bk[1] = r.y >> BSHIFT; rk[1] = atomicAdd(&cnt[bk[1]], 1);
      bk[2] = r.z >> BSHIFT; rk[2] = atomicAdd(&cnt[bk[2]], 1);
      bk[3] = r.w >> BSHIFT; rk[3] = atomicAdd(&cnt[bk[3]], 1);
    }
    __syncthreads();

    if (tid < NBKT) pos[tid] = atomicAdd(&bcnt[tid], cnt[tid]);
    if (tid == 0) {
      int run = 0;
      for (int b = 0; b < NBKT; ++b) { loff[b] = run; run += cnt[b]; }
      total = run;
    }
    __syncthreads();

    if (ok) {
      int src[4] = {c.x, c.y, c.z, c.w};
      int dst[4] = {r.x, r.y, r.z, r.w};
#pragma unroll
      for (int i = 0; i < 4; ++i) {
        int s = loff[bk[i]] + rk[i];
        lbuf[s] = (src[i] << BSHIFT) | (dst[i] & ((1 << BSHIFT) - 1));
        int g = pos[bk[i]] + rk[i];
        gaddr[s] = (g < CAP) ? bk[i] * CAP + g : -1;  // 16-sigma guard
      }
    }
    __syncthreads();

    int tot = total;
    for (int i = tid; i < tot; i += 512) {
      int g = gaddr[i];
      if (g >= 0) pairs[g] = lbuf[i];
    }
  } else if (bid < PA_BLOCKS + PACK_BLOCKS) {
    // ---- pack Wcat=[W_l;W_r] into MFMA B-fragment order.
    int t = (bid - PA_BLOCKS) * 512 + tid;  // t < 4096
    int Cb = t >> 9, kb = (t >> 6) & 7, lane = t & 63;
    int n = Cb * 16 + (lane & 15);
    int k0 = kb * 32 + (lane >> 4) * 8;
    ushort u[8];
#pragma unroll
    for (int j = 0; j < 8; ++j) {
      int k = k0 + j;
      float w = (k < C) ? W_l[k * C + n] : W_r[(k - C) * C + n];
      u[j] = f2bf(w);
    }
    ((uint4*)Bp)[t] = *(const uint4*)u;
  } else {
    // ---- cvt: x fp32 -> xh bf16 (77 MB stream).
    int t = (bid - PA_BLOCKS - PACK_BLOCKS) * 512 + tid;  // t < 1.6M exactly
    float4 a = ((const float4*)x)[2 * t];
    float4 b = ((const float4*)x)[2 * t + 1];
    ushort u[8] = {f2bf(a.x), f2bf(a.y), f2bf(a.z), f2bf(a.w),
                   f2bf(b.x), f2bf(b.y), f2bf(b.z), f2bf(b.w)};
    ((uint4*)xh)[t] = *(const uint4*)u;
  }
}

// ---------------------------------------------------------------------------
// passB: one block per bucket. Inline 98-wide scan of bcnt -> bucket base
// (bscan dispatch deleted). Then LDS node-count + scan -> off[], and scatter
// ssrc into the bucket's private ~64 KB L2-resident window.
// ---------------------------------------------------------------------------
__global__ __launch_bounds__(1024) void passB_kernel(
    const int* __restrict__ pairs, const int* __restrict__ bcnt,
    int* __restrict__ off, int* __restrict__ ssrc) {
  __shared__ int l[1024];
  __shared__ int cur[1024];
  __shared__ int s_gbase;
  int b = blockIdx.x, t = threadIdx.x;

  // Inline bucket-base scan (98 elements) in l[0:128).
  int v = 0;
  if (t < 128) {
    v = (t < NBKT) ? min(bcnt[t], CAP) : 0;
    l[t] = v;
  }
  __syncthreads();
  for (int d = 1; d < 128; d <<= 1) {
    int u = (t >= d && t < 128) ? l[t - d] : 0;
    __syncthreads();
    if (t < 128) l[t] += u;
    __syncthreads();
  }
  if (t == b) s_gbase = l[t] - v;  // exclusive prefix for this bucket
  __syncthreads();

  int nbase = b << BSHIFT;
  int nn = min(1024, N_NODES - nbase);
  int cntb = min(bcnt[b], CAP);
  int gbase = s_gbase;
  const int* bp = pairs + b * CAP;

  l[t] = 0;
  __syncthreads();
  for (int e = t; e < cntb; e += 1024) atomicAdd(&l[bp[e] & 1023], 1);
  __syncthreads();
  int own = l[t];
  for (int d = 1; d < 1024; d <<= 1) {  // inclusive Hillis-Steele
    int u = (t >= d) ? l[t - d] : 0;
    __syncthreads();
    l[t] += u;
    __syncthreads();
  }
  int excl = l[t] - own;
  if (t < nn) { off[nbase + t] = gbase + excl; cur[t] = excl; }
  if (b == NBKT - 1 && t == 1023) off[N_NODES] = gbase + l[1023];
  __syncthreads();
  for (int e = t; e < cntb; e += 1024) {
    int p = bp[e];
    int posn = atomicAdd(&cur[p & 1023], 1);
    ssrc[gbase + posn] = p >> BSHIFT;
  }
}

// ---------------------------------------------------------------------------
// Fused gather-mean + MFMA GEMM:  out = relu([agg|x] @ [W_l;W_r] + b_l)
// Gather: quarter-wave per edge-row (16 lanes x uint4 = 8 ch), now 4-deep
// unroll -> 16 edges in flight per wave (latency-bound per R6 counters).
// ---------------------------------------------------------------------------
__global__ __launch_bounds__(256) void fused_kernel(
    const ushort* __restrict__ xh, const int* __restrict__ off,
    const int* __restrict__ ssrc, const ushort* __restrict__ Bp,
    const float* __restrict__ b_l, float* __restrict__ out) {
  __shared__ ushort lA[32][264];
  int tid = threadIdx.x;
  int lane = tid & 63;
  int wave = tid >> 6;
  long base = (long)blockIdx.x * 32;

  // Stage this block's own 32 bf16 x-rows into cols [128,256).
  for (int i = tid; i < 32 * 16; i += 256) {
    int r = i >> 4, q = i & 15;
    uint4 v = ((const uint4*)(xh + (base + r) * C))[q];
    *(uint4*)&lA[r][128 + q * 8] = v;
  }

  int l4 = lane & 15;   // channel group: ch [l4*8, l4*8+8)
  int q = lane >> 4;    // quarter: edge stripe

  for (int j = 0; j < 8; ++j) {
    int n = wave * 8 + j;
    long row = base + n;
    int e0 = off[row];
    int e1 = off[row + 1];
    float s[8];
#pragma unroll
    for (int i = 0; i < 8; ++i) s[i] = 0.0f;

    int e = e0 + q;
    for (; e + 12 < e1; e += 16) {  // 4 uint4 loads in flight per lane
      int sa = ssrc[e], sb = ssrc[e + 4], sc = ssrc[e + 8], sd = ssrc[e + 12];
      uint4 va = ((const uint4*)(xh + (long)sa * C))[l4];
      uint4 vb = ((const uint4*)(xh + (long)sb * C))[l4];
      uint4 vc = ((const uint4*)(xh + (long)sc * C))[l4];
      uint4 vd = ((const uint4*)(xh + (long)sd * C))[l4];
      s[0] += (bflo(va.x) + bflo(vb.x)) + (bflo(vc.x) + bflo(vd.x));
      s[1] += (bfhi(va.x) + bfhi(vb.x)) + (bfhi(vc.x) + bfhi(vd.x));
      s[2] += (bflo(va.y) + bflo(vb.y)) + (bflo(vc.y) + bflo(vd.y));
      s[3] += (bfhi(va.y) + bfhi(vb.y)) + (bfhi(vc.y) + bfhi(vd.y));
      s[4] += (bflo(va.z) + bflo(vb.z)) + (bflo(vc.z) + bflo(vd.z));
      s[5] += (bfhi(va.z) + bfhi(vb.z)) + (bfhi(vc.z) + bfhi(vd.z));
      s[6] += (bflo(va.w) + bflo(vb.w)) + (bflo(vc.w) + bflo(vd.w));
      s[7] += (bfhi(va.w) + bfhi(vb.w)) + (bfhi(vc.w) + bfhi(vd.w));
    }
    for (; e + 4 < e1; e += 8) {  // 2-deep
      int sa = ssrc[e], sb = ssrc[e + 4];
      uint4 va = ((const uint4*)(xh + (long)sa * C))[l4];
      uint4 vb = ((const uint4*)(xh + (long)sb * C))[l4];
      s[0] += bflo(va.x) + bflo(vb.x); s[1] += bfhi(va.x) + bfhi(vb.x);
      s[2] += bflo(va.y) + bflo(vb.y); s[3] += bfhi(va.y) + bfhi(vb.y);
      s[4] += bflo(va.z) + bflo(vb.z); s[5] += bfhi(va.z) + bfhi(vb.z);
      s[6] += bflo(va.w) + bflo(vb.w); s[7] += bfhi(va.w) + bfhi(vb.w);
    }
    if (e < e1) {  // at most one stripe element left
      int sa = ssrc[e];
      uint4 va = ((const uint4*)(xh + (long)sa * C))[l4];
      s[0] += bflo(va.x); s[1] += bfhi(va.x);
      s[2] += bflo(va.y); s[3] += bfhi(va.y);
      s[4] += bflo(va.z); s[5] += bfhi(va.z);
      s[6] += bflo(va.w); s[7] += bfhi(va.w);
    }
#pragma unroll
    for (int i = 0; i < 8; ++i) {
      s[i] += __shfl_xor(s[i], 16);
      s[i] += __shfl_xor(s[i], 32);
    }
    float inv = 1.0f / fmaxf((float)(e1 - e0), 1.0f);
    if (q == 0) {
      ushort u[8];
#pragma unroll
      for (int i = 0; i < 8; ++i) u[i] = f2bf(s[i] * inv);
      *(uint4*)&lA[n][l4 * 8] = *(const uint4*)u;
    }
  }
  __syncthreads();

  // MFMA: wave w owns col-tiles Cb in {2w, 2w+1}, row-tiles R in {0,1}.
  f32x4 acc0 = {0, 0, 0, 0}, acc1 = {0, 0, 0, 0};
  f32x4 acc2 = {0, 0, 0, 0}, acc3 = {0, 0, 0, 0};
  int m = lane & 15, quad = lane >> 4;
  const ushort* bp0 = Bp + (((2 * wave + 0) * 8) * 64 + lane) * 8;
  const ushort* bp1 = Bp + (((2 * wave + 1) * 8) * 64 + lane) * 8;
#pragma unroll
  for (int kb = 0; kb < 8; ++kb) {
    short8 a0 = *(const short8*)&lA[m][kb * 32 + quad * 8];
    short8 a1 = *(const short8*)&lA[16 + m][kb * 32 + quad * 8];
    short8 b0 = *(const short8*)(bp0 + kb * 64 * 8);
    short8 b1 = *(const short8*)(bp1 + kb * 64 * 8);
    acc0 = __builtin_amdgcn_mfma_f32_16x16x32_bf16(a0, b0, acc0, 0, 0, 0);
    acc1 = __builtin_amdgcn_mfma_f32_16x16x32_bf16(a0, b1, acc1, 0, 0, 0);
    acc2 = __builtin_amdgcn_mfma_f32_16x16x32_bf16(a1, b0, acc2, 0, 0, 0);
    acc3 = __builtin_amdgcn_mfma_f32_16x16x32_bf16(a1, b1, acc3, 0, 0, 0);
  }

  int col0 = (2 * wave + 0) * 16 + m;
  int col1 = col0 + 16;
  float bl0 = b_l[col0], bl1 = b_l[col1];
#pragma unroll
  for (int r = 0; r < 4; ++r) {
    long row0 = base + quad * 4 + r;
    long row1 = row0 + 16;
    out[row0 * C + col0] = fmaxf(acc0[r] + bl0, 0.0f);
    out[row0 * C + col1] = fmaxf(acc1[r] + bl1, 0.0f);
    out[row1 * C + col0] = fmaxf(acc2[r] + bl0, 0.0f);
    out[row1 * C + col1] = fmaxf(acc3[r] + bl1, 0.0f);
  }
}

extern "C" void kernel_launch(void* const* d_in, const int* in_sizes, int n_in,
                              void* d_out, int out_size, void* d_ws, size_t ws_size,
                              hipStream_t stream) {
  const float* x   = (const float*)d_in[0];
  const int* erow  = (const int*)d_in[1];   // dst
  const int* ecol  = (const int*)d_in[2];   // src
  const float* W_l = (const float*)d_in[3];
  const float* b_l = (const float*)d_in[4];
  const float* W_r = (const float*)d_in[5];
  float* out = (float*)d_out;

  // ws layout (16B-aligned segments), ~40 MB total:
  char* p = (char*)d_ws;
  ushort* xh  = (ushort*)p;  p += (size_t)N_NODES * C * 2;      // 25.6 MB
  ushort* Bp  = (ushort*)p;  p += 2 * C * C * 2;                // 64 KB
  int* off    = (int*)p;     p += (size_t)(N_NODES + 4) * 4;    // 400 KB
  int* pairs  = (int*)p;     p += (size_t)NBKT * CAP * 4;       // 7.2 MB
  int* ssrc   = (int*)p;     p += (size_t)E_EDGES * 4;          // 6.4 MB
  int* bcnt   = (int*)p;

  hipMemsetAsync(bcnt, 0, NBKT * sizeof(int), stream);
  mega_kernel<<<PA_BLOCKS + PACK_BLOCKS + CVT_BLOCKS, 512, 0, stream>>>(
      x, erow, ecol, W_l, W_r, xh, Bp, bcnt, pairs);
  passB_kernel<<<NBKT, 1024, 0, stream>>>(pairs, bcnt, off, ssrc);
  fused_kernel<<<N_NODES / 32, 256, 0, stream>>>(xh, off, ssrc, Bp, b_l, out);
}

// Round 8
// 222.295 us; speedup vs baseline: 1.0719x; 1.0719x over previous
//
#include <hip/hip_runtime.h>

#define N_NODES 100000
#define E_EDGES 1600000
#define C 128
#define BSHIFT 9
#define BMASK 511
#define BNODES 512
#define NBKT 196      // ceil(N/512)
#define CAP 9728      // mean 8163, sigma ~90 -> +17 sigma

#define PA_BLOCKS 782     // passA role: 2048 edges per 512-thr block
#define PACK_BLOCKS 8     // pack role: 4096 frag-items
#define CVT_BLOCKS 3125   // cvt role: 1.6M uint4

typedef __attribute__((ext_vector_type(8))) short short8;   // 8 bf16 (4 VGPRs)
typedef __attribute__((ext_vector_type(4))) float f32x4;    // MFMA acc

__device__ __forceinline__ unsigned short f2bf(float f) {  // RNE fp32->bf16
  unsigned int b = __float_as_uint(f);
  return (unsigned short)((b + 0x7fffu + ((b >> 16) & 1u)) >> 16);
}
__device__ __forceinline__ float bflo(unsigned int v) {
  return __uint_as_float(v << 16);
}
__device__ __forceinline__ float bfhi(unsigned int v) {
  return __uint_as_float(v & 0xffff0000u);
}

// ---------------------------------------------------------------------------
// mega: passA (multisplit by dst>>9) + W-pack + x->bf16 cvt, one dispatch.
// ---------------------------------------------------------------------------
__global__ __launch_bounds__(512) void mega_kernel(
    const float* __restrict__ x, const int* __restrict__ erow,
    const int* __restrict__ ecol, const float* __restrict__ W_l,
    const float* __restrict__ W_r, ushort* __restrict__ xh,
    ushort* __restrict__ Bp, int* __restrict__ bcnt, int* __restrict__ pairs) {
  __shared__ int cnt[NBKT], pos[NBKT], loff[NBKT], total;
  __shared__ int lbuf[2048];
  __shared__ int gaddr[2048];
  int bid = blockIdx.x;
  int tid = threadIdx.x;

  if (bid < PA_BLOCKS) {
    // ---- passA: LDS 196-way split, one global atomic per bucket per block,
    //      bucket-ordered ~42 B runs into fixed-CAP regions of `pairs`.
    for (int b = tid; b < NBKT; b += 512) cnt[b] = 0;
    __syncthreads();

    int idx = bid * 512 + tid;  // int4 index: edges [4*idx, 4*idx+4)
    bool ok = (idx < E_EDGES / 4);
    int4 r, c;
    int bk[4], rk[4];
    if (ok) {
      r = ((const int4*)erow)[idx];
      c = ((const int4*)ecol)[idx];
      bk[0] = r.x >> BSHIFT; rk[0] = atomicAdd(&cnt[bk[0]], 1);
      bk[1] = r.y >> BSHIFT; rk[1] = atomicAdd(&cnt[bk[1]], 1);
      bk[2] = r.z >> BSHIFT; rk[2] = atomicAdd(&cnt[bk[2]], 1);
      bk[3] = r.w >> BSHIFT; rk[3] = atomicAdd(&cnt[bk[3]], 1);
    }
    __syncthreads();

    if (tid < NBKT) pos[tid] = atomicAdd(&bcnt[tid], cnt[tid]);
    if (tid == 0) {
      int run = 0;
      for (int b = 0; b < NBKT; ++b) { loff[b] = run; run += cnt[b]; }
      total = run;
    }
    __syncthreads();

    if (ok) {
      int src[4] = {c.x, c.y, c.z, c.w};
      int dst[4] = {r.x, r.y, r.z, r.w};
#pragma unroll
      for (int i = 0; i < 4; ++i) {
        int s = loff[bk[i]] + rk[i];
        lbuf[s] = (src[i] << BSHIFT) | (dst[i] & BMASK);
        int g = pos[bk[i]] + rk[i];
        gaddr[s] = (g < CAP) ? bk[i] * CAP + g : -1;  // 17-sigma guard
      }
    }
    __syncthreads();

    int tot = total;
    for (int i = tid; i < tot; i += 512) {
      int g = gaddr[i];
      if (g >= 0) pairs[g] = lbuf[i];
    }
  } else if (bid < PA_BLOCKS + PACK_BLOCKS) {
    // ---- pack Wcat=[W_l;W_r] into MFMA B-fragment order.
    int t = (bid - PA_BLOCKS) * 512 + tid;  // t < 4096
    int Cb = t >> 9, kb = (t >> 6) & 7, lane = t & 63;
    int n = Cb * 16 + (lane & 15);
    int k0 = kb * 32 + (lane >> 4) * 8;
    ushort u[8];
#pragma unroll
    for (int j = 0; j < 8; ++j) {
      int k = k0 + j;
      float w = (k < C) ? W_l[k * C + n] : W_r[(k - C) * C + n];
      u[j] = f2bf(w);
    }
    ((uint4*)Bp)[t] = *(const uint4*)u;
  } else {
    // ---- cvt: x fp32 -> xh bf16 (77 MB stream).
    int t = (bid - PA_BLOCKS - PACK_BLOCKS) * 512 + tid;  // t < 1.6M exactly
    float4 a = ((const float4*)x)[2 * t];
    float4 b = ((const float4*)x)[2 * t + 1];
    ushort u[8] = {f2bf(a.x), f2bf(a.y), f2bf(a.z), f2bf(a.w),
                   f2bf(b.x), f2bf(b.y), f2bf(b.z), f2bf(b.w)};
    ((uint4*)xh)[t] = *(const uint4*)u;
  }
}

// ---------------------------------------------------------------------------
// passB: one 512-thr block per 512-node bucket (196 blocks -> 2x machine
// fill vs R7's 98x1024). Inline 196-wide scan of bcnt -> bucket base; LDS
// node-count + scan -> off[]; scatter ssrc into the bucket's private ~32 KB
// L2-resident window.
// ---------------------------------------------------------------------------
__global__ __launch_bounds__(512) void passB_kernel(
    const int* __restrict__ pairs, const int* __restrict__ bcnt,
    int* __restrict__ off, int* __restrict__ ssrc) {
  __shared__ int l[512];
  __shared__ int cur[512];
  __shared__ int s_gbase;
  int b = blockIdx.x, t = threadIdx.x;

  // Inline bucket-base scan (196 elements) in l[0:256).
  int v = 0;
  if (t < 256) {
    v = (t < NBKT) ? min(bcnt[t], CAP) : 0;
    l[t] = v;
  }
  __syncthreads();
  for (int d = 1; d < 256; d <<= 1) {
    int u = (t >= d && t < 256) ? l[t - d] : 0;
    __syncthreads();
    if (t < 256) l[t] += u;
    __syncthreads();
  }
  if (t == b) s_gbase = l[t] - v;  // exclusive prefix for this bucket
  __syncthreads();

  int nbase = b << BSHIFT;
  int nn = min(BNODES, N_NODES - nbase);
  int cntb = min(bcnt[b], CAP);
  int gbase = s_gbase;
  const int* bp = pairs + b * CAP;

  l[t] = 0;
  __syncthreads();
  for (int e = t; e < cntb; e += 512) atomicAdd(&l[bp[e] & BMASK], 1);
  __syncthreads();
  int own = l[t];
  for (int d = 1; d < 512; d <<= 1) {  // inclusive Hillis-Steele
    int u = (t >= d) ? l[t - d] : 0;
    __syncthreads();
    l[t] += u;
    __syncthreads();
  }
  int excl = l[t] - own;
  if (t < nn) { off[nbase + t] = gbase + excl; cur[t] = excl; }
  if (b == NBKT - 1 && t == 511) off[N_NODES] = gbase + l[511];
  __syncthreads();
  for (int e = t; e < cntb; e += 512) {
    int p = bp[e];
    int posn = atomicAdd(&cur[p & BMASK], 1);
    ssrc[gbase + posn] = p >> BSHIFT;
  }
}

// ---------------------------------------------------------------------------
// Fused gather-mean + MFMA GEMM:  out = relu([agg|x] @ [W_l;W_r] + b_l)
// Gather: quarter-wave per edge-row (16 lanes x uint4 = 8 ch), 2-deep unroll
// (R6 form; R7's 4-deep raised VGPR 32->40, occupancy 64->48%, fused +12us).
// ---------------------------------------------------------------------------
__global__ __launch_bounds__(256) void fused_kernel(
    const ushort* __restrict__ xh, const int* __restrict__ off,
    const int* __restrict__ ssrc, const ushort* __restrict__ Bp,
    const float* __restrict__ b_l, float* __restrict__ out) {
  __shared__ ushort lA[32][264];
  int tid = threadIdx.x;
  int lane = tid & 63;
  int wave = tid >> 6;
  long base = (long)blockIdx.x * 32;

  // Stage this block's own 32 bf16 x-rows into cols [128,256).
  for (int i = tid; i < 32 * 16; i += 256) {
    int r = i >> 4, q = i & 15;
    uint4 v = ((const uint4*)(xh + (base + r) * C))[q];
    *(uint4*)&lA[r][128 + q * 8] = v;
  }

  int l4 = lane & 15;   // channel group: ch [l4*8, l4*8+8)
  int q = lane >> 4;    // quarter: edge stripe

  for (int j = 0; j < 8; ++j) {
    int n = wave * 8 + j;
    long row = base + n;
    int e0 = off[row];
    int e1 = off[row + 1];
    float s[8];
#pragma unroll
    for (int i = 0; i < 8; ++i) s[i] = 0.0f;

    int e = e0 + q;
    for (; e + 4 < e1; e += 8) {  // 2 uint4 loads in flight per lane
      int sa = ssrc[e];
      int sb = ssrc[e + 4];
      uint4 va = ((const uint4*)(xh + (long)sa * C))[l4];
      uint4 vb = ((const uint4*)(xh + (long)sb * C))[l4];
      s[0] += bflo(va.x) + bflo(vb.x); s[1] += bfhi(va.x) + bfhi(vb.x);
      s[2] += bflo(va.y) + bflo(vb.y); s[3] += bfhi(va.y) + bfhi(vb.y);
      s[4] += bflo(va.z) + bflo(vb.z); s[5] += bfhi(va.z) + bfhi(vb.z);
      s[6] += bflo(va.w) + bflo(vb.w); s[7] += bfhi(va.w) + bfhi(vb.w);
    }
    if (e < e1) {  // tail: at most one more stripe element
      int sa = ssrc[e];
      uint4 va = ((const uint4*)(xh + (long)sa * C))[l4];
      s[0] += bflo(va.x); s[1] += bfhi(va.x);
      s[2] += bflo(va.y); s[3] += bfhi(va.y);
      s[4] += bflo(va.z); s[5] += bfhi(va.z);
      s[6] += bflo(va.w); s[7] += bfhi(va.w);
    }
#pragma unroll
    for (int i = 0; i < 8; ++i) {
      s[i] += __shfl_xor(s[i], 16);
      s[i] += __shfl_xor(s[i], 32);
    }
    float inv = 1.0f / fmaxf((float)(e1 - e0), 1.0f);
    if (q == 0) {
      ushort u[8];
#pragma unroll
      for (int i = 0; i < 8; ++i) u[i] = f2bf(s[i] * inv);
      *(uint4*)&lA[n][l4 * 8] = *(const uint4*)u;
    }
  }
  __syncthreads();

  // MFMA: wave w owns col-tiles Cb in {2w, 2w+1}, row-tiles R in {0,1}.
  f32x4 acc0 = {0, 0, 0, 0}, acc1 = {0, 0, 0, 0};
  f32x4 acc2 = {0, 0, 0, 0}, acc3 = {0, 0, 0, 0};
  int m = lane & 15, quad = lane >> 4;
  const ushort* bp0 = Bp + (((2 * wave + 0) * 8) * 64 + lane) * 8;
  const ushort* bp1 = Bp + (((2 * wave + 1) * 8) * 64 + lane) * 8;
#pragma unroll
  for (int kb = 0; kb < 8; ++kb) {
    short8 a0 = *(const short8*)&lA[m][kb * 32 + quad * 8];
    short8 a1 = *(const short8*)&lA[16 + m][kb * 32 + quad * 8];
    short8 b0 = *(const short8*)(bp0 + kb * 64 * 8);
    short8 b1 = *(const short8*)(bp1 + kb * 64 * 8);
    acc0 = __builtin_amdgcn_mfma_f32_16x16x32_bf16(a0, b0, acc0, 0, 0, 0);
    acc1 = __builtin_amdgcn_mfma_f32_16x16x32_bf16(a0, b1, acc1, 0, 0, 0);
    acc2 = __builtin_amdgcn_mfma_f32_16x16x32_bf16(a1, b0, acc2, 0, 0, 0);
    acc3 = __builtin_amdgcn_mfma_f32_16x16x32_bf16(a1, b1, acc3, 0, 0, 0);
  }

  int col0 = (2 * wave + 0) * 16 + m;
  int col1 = col0 + 16;
  float bl0 = b_l[col0], bl1 = b_l[col1];
#pragma unroll
  for (int r = 0; r < 4; ++r) {
    long row0 = base + quad * 4 + r;
    long row1 = row0 + 16;
    out[row0 * C + col0] = fmaxf(acc0[r] + bl0, 0.0f);
    out[row0 * C + col1] = fmaxf(acc1[r] + bl1, 0.0f);
    out[row1 * C + col0] = fmaxf(acc2[r] + bl0, 0.0f);
    out[row1 * C + col1] = fmaxf(acc3[r] + bl1, 0.0f);
  }
}

extern "C" void kernel_launch(void* const* d_in, const int* in_sizes, int n_in,
                              void* d_out, int out_size, void* d_ws, size_t ws_size,
                              hipStream_t stream) {
  const float* x   = (const float*)d_in[0];
  const int* erow  = (const int*)d_in[1];   // dst
  const int* ecol  = (const int*)d_in[2];   // src
  const float* W_l = (const float*)d_in[3];
  const float* b_l = (const float*)d_in[4];
  const float* W_r = (const float*)d_in[5];
  float* out = (float*)d_out;

  // ws layout (16B-aligned segments), ~40 MB total:
  char* p = (char*)d_ws;
  ushort* xh  = (ushort*)p;  p += (size_t)N_NODES * C * 2;      // 25.6 MB
  ushort* Bp  = (ushort*)p;  p += 2 * C * C * 2;                // 64 KB
  int* off    = (int*)p;     p += (size_t)(N_NODES + 4) * 4;    // 400 KB
  int* pairs  = (int*)p;     p += (size_t)NBKT * CAP * 4;       // 7.6 MB
  int* ssrc   = (int*)p;     p += (size_t)E_EDGES * 4;          // 6.4 MB
  int* bcnt   = (int*)p;

  hipMemsetAsync(bcnt, 0, NBKT * sizeof(int), stream);
  mega_kernel<<<PA_BLOCKS + PACK_BLOCKS + CVT_BLOCKS, 512, 0, stream>>>(
      x, erow, ecol, W_l, W_r, xh, Bp, bcnt, pairs);
  passB_kernel<<<NBKT, 512, 0, stream>>>(pairs, bcnt, off, ssrc);
  fused_kernel<<<N_NODES / 32, 256, 0, stream>>>(xh, off, ssrc, Bp, b_l, out);
}

// Round 9
// 208.853 us; speedup vs baseline: 1.1409x; 1.0644x over previous
//
#include <hip/hip_runtime.h>

#define N_NODES 100000
#define E_EDGES 1600000
#define C 128
#define BSHIFT 9
#define BMASK 511
#define BNODES 512
#define NBKT 196      // ceil(N/512)
#define CAP 9728      // mean 8192, sigma ~90 -> +17 sigma

#define PA_BLOCKS 391     // passA role: 4096 edges per 512-thr block
#define PACK_BLOCKS 8     // pack role: 4096 frag-items
#define CVT_BLOCKS 3125   // cvt role: 1.6M uint4

typedef __attribute__((ext_vector_type(8))) short short8;   // 8 bf16 (4 VGPRs)
typedef __attribute__((ext_vector_type(4))) float f32x4;    // MFMA acc

__device__ __forceinline__ unsigned short f2bf(float f) {  // RNE fp32->bf16
  unsigned int b = __float_as_uint(f);
  return (unsigned short)((b + 0x7fffu + ((b >> 16) & 1u)) >> 16);
}
__device__ __forceinline__ float bflo(unsigned int v) {
  return __uint_as_float(v << 16);
}
__device__ __forceinline__ float bfhi(unsigned int v) {
  return __uint_as_float(v & 0xffff0000u);
}

// ---------------------------------------------------------------------------
// mega: passA (multisplit by dst>>9) + W-pack + x->bf16 cvt, one dispatch.
// passA fixes vs R8: 4096 edges/block (fewer blocks -> fewer bcnt atomics,
// fewer scans) and PARALLEL 8-round LDS scan (R8 had a serial 196-iter loop
// at tid==0, ~8k dependent cycles with the whole block parked).
// ---------------------------------------------------------------------------
__global__ __launch_bounds__(512) void mega_kernel(
    const float* __restrict__ x, const int* __restrict__ erow,
    const int* __restrict__ ecol, const float* __restrict__ W_l,
    const float* __restrict__ W_r, ushort* __restrict__ xh,
    ushort* __restrict__ Bp, int* __restrict__ bcnt, int* __restrict__ pairs) {
  __shared__ int cnt[NBKT], pos[NBKT], loff[256], total;
  __shared__ int lbuf[4096];
  __shared__ int gaddr[4096];
  int bid = blockIdx.x;
  int tid = threadIdx.x;

  if (bid < PA_BLOCKS) {
    for (int b = tid; b < NBKT; b += 512) cnt[b] = 0;
    __syncthreads();

    // Two int4s per thread, strided for coalescing: edges [bid*4096, +4096).
    int i0 = bid * 1024 + tid;
    int i1 = i0 + 512;
    bool ok0 = (i0 < E_EDGES / 4), ok1 = (i1 < E_EDGES / 4);
    int4 r0, c0, r1, c1;
    int bk[8], rk[8];
    if (ok0) {
      r0 = ((const int4*)erow)[i0];
      c0 = ((const int4*)ecol)[i0];
      bk[0] = r0.x >> BSHIFT; rk[0] = atomicAdd(&cnt[bk[0]], 1);
      bk[1] = r0.y >> BSHIFT; rk[1] = atomicAdd(&cnt[bk[1]], 1);
      bk[2] = r0.z >> BSHIFT; rk[2] = atomicAdd(&cnt[bk[2]], 1);
      bk[3] = r0.w >> BSHIFT; rk[3] = atomicAdd(&cnt[bk[3]], 1);
    }
    if (ok1) {
      r1 = ((const int4*)erow)[i1];
      c1 = ((const int4*)ecol)[i1];
      bk[4] = r1.x >> BSHIFT; rk[4] = atomicAdd(&cnt[bk[4]], 1);
      bk[5] = r1.y >> BSHIFT; rk[5] = atomicAdd(&cnt[bk[5]], 1);
      bk[6] = r1.z >> BSHIFT; rk[6] = atomicAdd(&cnt[bk[6]], 1);
      bk[7] = r1.w >> BSHIFT; rk[7] = atomicAdd(&cnt[bk[7]], 1);
    }
    __syncthreads();

    // Global per-bucket chunk alloc + parallel exclusive scan of cnt -> loff.
    int v = 0;
    if (tid < 256) {
      v = (tid < NBKT) ? cnt[tid] : 0;
      loff[tid] = v;
      if (tid < NBKT) pos[tid] = atomicAdd(&bcnt[tid], v);
    }
    __syncthreads();
    for (int d = 1; d < 256; d <<= 1) {
      int u = (tid < 256 && tid >= d) ? loff[tid - d] : 0;
      __syncthreads();
      if (tid < 256) loff[tid] += u;
      __syncthreads();
    }
    if (tid < 256) loff[tid] -= v;  // own-slot exclusive (no race)
    if (tid == NBKT - 1) total = loff[tid] + v;
    __syncthreads();

    if (ok0) {
      int src[4] = {c0.x, c0.y, c0.z, c0.w};
      int dst[4] = {r0.x, r0.y, r0.z, r0.w};
#pragma unroll
      for (int i = 0; i < 4; ++i) {
        int s = loff[bk[i]] + rk[i];
        lbuf[s] = (src[i] << BSHIFT) | (dst[i] & BMASK);
        int g = pos[bk[i]] + rk[i];
        gaddr[s] = (g < CAP) ? bk[i] * CAP + g : -1;  // 17-sigma guard
      }
    }
    if (ok1) {
      int src[4] = {c1.x, c1.y, c1.z, c1.w};
      int dst[4] = {r1.x, r1.y, r1.z, r1.w};
#pragma unroll
      for (int i = 0; i < 4; ++i) {
        int s = loff[bk[4 + i]] + rk[4 + i];
        lbuf[s] = (src[i] << BSHIFT) | (dst[i] & BMASK);
        int g = pos[bk[4 + i]] + rk[4 + i];
        gaddr[s] = (g < CAP) ? bk[4 + i] * CAP + g : -1;
      }
    }
    __syncthreads();

    int tot = total;
    for (int i = tid; i < tot; i += 512) {
      int g = gaddr[i];
      if (g >= 0) pairs[g] = lbuf[i];  // ~84 B bucket-ordered runs
    }
  } else if (bid < PA_BLOCKS + PACK_BLOCKS) {
    // ---- pack Wcat=[W_l;W_r] into MFMA B-fragment order.
    int t = (bid - PA_BLOCKS) * 512 + tid;  // t < 4096
    int Cb = t >> 9, kb = (t >> 6) & 7, lane = t & 63;
    int n = Cb * 16 + (lane & 15);
    int k0 = kb * 32 + (lane >> 4) * 8;
    ushort u[8];
#pragma unroll
    for (int j = 0; j < 8; ++j) {
      int k = k0 + j;
      float w = (k < C) ? W_l[k * C + n] : W_r[(k - C) * C + n];
      u[j] = f2bf(w);
    }
    ((uint4*)Bp)[t] = *(const uint4*)u;
  } else {
    // ---- cvt: x fp32 -> xh bf16 (77 MB stream).
    int t = (bid - PA_BLOCKS - PACK_BLOCKS) * 512 + tid;  // t < 1.6M exactly
    float4 a = ((const float4*)x)[2 * t];
    float4 b = ((const float4*)x)[2 * t + 1];
    ushort u[8] = {f2bf(a.x), f2bf(a.y), f2bf(a.z), f2bf(a.w),
                   f2bf(b.x), f2bf(b.y), f2bf(b.z), f2bf(b.w)};
    ((uint4*)xh)[t] = *(const uint4*)u;
  }
}

// ---------------------------------------------------------------------------
// passB: one 1024-thr block per 512-node bucket (16 waves/CU for latency
// hiding, was 8). Single global pass: stage the bucket's pairs into LDS
// (38 KB), then count+scan+scatter entirely from LDS. ssrc writes confined
// to the bucket's private ~32 KB L2-resident window.
// ---------------------------------------------------------------------------
__global__ __launch_bounds__(1024) void passB_kernel(
    const int* __restrict__ pairs, const int* __restrict__ bcnt,
    int* __restrict__ off, int* __restrict__ ssrc) {
  __shared__ int lds_pairs[CAP];
  __shared__ int l[512];
  __shared__ int cur[512];
  __shared__ int s_gbase;
  int b = blockIdx.x, t = threadIdx.x;

  // Inline bucket-base scan (196 elements) using first 256 threads.
  int v = 0;
  if (t < 256) {
    v = (t < NBKT) ? min(bcnt[t], CAP) : 0;
    l[t < 512 ? t : 0] = 0;  // noop shape; real init below
  }
  __shared__ int bs[256];
  if (t < 256) bs[t] = v;
  __syncthreads();
  for (int d = 1; d < 256; d <<= 1) {
    int u = (t < 256 && t >= d) ? bs[t - d] : 0;
    __syncthreads();
    if (t < 256) bs[t] += u;
    __syncthreads();
  }
  if (t == b) s_gbase = bs[t] - v;  // exclusive prefix (b < 196 < 256)
  if (t < 512) l[t] = 0;
  __syncthreads();

  int nbase = b << BSHIFT;
  int nn = min(BNODES, N_NODES - nbase);
  int cntb = min(bcnt[b], CAP);
  int gbase = s_gbase;
  const int* bp = pairs + b * CAP;

  // Stage + count in one global pass.
  for (int e = t; e < cntb; e += 1024) {
    int p = bp[e];
    lds_pairs[e] = p;
    atomicAdd(&l[p & BMASK], 1);
  }
  __syncthreads();

  int own = (t < 512) ? l[t] : 0;
  for (int d = 1; d < 512; d <<= 1) {  // inclusive Hillis-Steele over 512
    int u = (t < 512 && t >= d) ? l[t - d] : 0;
    __syncthreads();
    if (t < 512) l[t] += u;
    __syncthreads();
  }
  if (t < 512) {
    int excl = l[t] - own;
    if (t < nn) off[nbase + t] = gbase + excl;
    cur[t] = excl;
  }
  if (b == NBKT - 1 && t == 1023) off[N_NODES] = gbase + l[511];
  __syncthreads();

  for (int e = t; e < cntb; e += 1024) {
    int p = lds_pairs[e];
    int posn = atomicAdd(&cur[p & BMASK], 1);
    ssrc[gbase + posn] = p >> BSHIFT;
  }
}

// ---------------------------------------------------------------------------
// Fused gather-mean + MFMA GEMM:  out = relu([agg|x] @ [W_l;W_r] + b_l)
// (R8 form, unchanged: 2-deep uint4 quarter-wave gather, VGPR 32, Occ 63%.)
// ---------------------------------------------------------------------------
__global__ __launch_bounds__(256) void fused_kernel(
    const ushort* __restrict__ xh, const int* __restrict__ off,
    const int* __restrict__ ssrc, const ushort* __restrict__ Bp,
    const float* __restrict__ b_l, float* __restrict__ out) {
  __shared__ ushort lA[32][264];
  int tid = threadIdx.x;
  int lane = tid & 63;
  int wave = tid >> 6;
  long base = (long)blockIdx.x * 32;

  for (int i = tid; i < 32 * 16; i += 256) {
    int r = i >> 4, q = i & 15;
    uint4 v = ((const uint4*)(xh + (base + r) * C))[q];
    *(uint4*)&lA[r][128 + q * 8] = v;
  }

  int l4 = lane & 15;   // channel group: ch [l4*8, l4*8+8)
  int q = lane >> 4;    // quarter: edge stripe

  for (int j = 0; j < 8; ++j) {
    int n = wave * 8 + j;
    long row = base + n;
    int e0 = off[row];
    int e1 = off[row + 1];
    float s[8];
#pragma unroll
    for (int i = 0; i < 8; ++i) s[i] = 0.0f;

    int e = e0 + q;
    for (; e + 4 < e1; e += 8) {  // 2 uint4 loads in flight per lane
      int sa = ssrc[e];
      int sb = ssrc[e + 4];
      uint4 va = ((const uint4*)(xh + (long)sa * C))[l4];
      uint4 vb = ((const uint4*)(xh + (long)sb * C))[l4];
      s[0] += bflo(va.x) + bflo(vb.x); s[1] += bfhi(va.x) + bfhi(vb.x);
      s[2] += bflo(va.y) + bflo(vb.y); s[3] += bfhi(va.y) + bfhi(vb.y);
      s[4] += bflo(va.z) + bflo(vb.z); s[5] += bfhi(va.z) + bfhi(vb.z);
      s[6] += bflo(va.w) + bflo(vb.w); s[7] += bfhi(va.w) + bfhi(vb.w);
    }
    if (e < e1) {
      int sa = ssrc[e];
      uint4 va = ((const uint4*)(xh + (long)sa * C))[l4];
      s[0] += bflo(va.x); s[1] += bfhi(va.x);
      s[2] += bflo(va.y); s[3] += bfhi(va.y);
      s[4] += bflo(va.z); s[5] += bfhi(va.z);
      s[6] += bflo(va.w); s[7] += bfhi(va.w);
    }
#pragma unroll
    for (int i = 0; i < 8; ++i) {
      s[i] += __shfl_xor(s[i], 16);
      s[i] += __shfl_xor(s[i], 32);
    }
    float inv = 1.0f / fmaxf((float)(e1 - e0), 1.0f);
    if (q == 0) {
      ushort u[8];
#pragma unroll
      for (int i = 0; i < 8; ++i) u[i] = f2bf(s[i] * inv);
      *(uint4*)&lA[n][l4 * 8] = *(const uint4*)u;
    }
  }
  __syncthreads();

  f32x4 acc0 = {0, 0, 0, 0}, acc1 = {0, 0, 0, 0};
  f32x4 acc2 = {0, 0, 0, 0}, acc3 = {0, 0, 0, 0};
  int m = lane & 15, quad = lane >> 4;
  const ushort* bp0 = Bp + (((2 * wave + 0) * 8) * 64 + lane) * 8;
  const ushort* bp1 = Bp + (((2 * wave + 1) * 8) * 64 + lane) * 8;
#pragma unroll
  for (int kb = 0; kb < 8; ++kb) {
    short8 a0 = *(const short8*)&lA[m][kb * 32 + quad * 8];
    short8 a1 = *(const short8*)&lA[16 + m][kb * 32 + quad * 8];
    short8 b0 = *(const short8*)(bp0 + kb * 64 * 8);
    short8 b1 = *(const short8*)(bp1 + kb * 64 * 8);
    acc0 = __builtin_amdgcn_mfma_f32_16x16x32_bf16(a0, b0, acc0, 0, 0, 0);
    acc1 = __builtin_amdgcn_mfma_f32_16x16x32_bf16(a0, b1, acc1, 0, 0, 0);
    acc2 = __builtin_amdgcn_mfma_f32_16x16x32_bf16(a1, b0, acc2, 0, 0, 0);
    acc3 = __builtin_amdgcn_mfma_f32_16x16x32_bf16(a1, b1, acc3, 0, 0, 0);
  }

  int col0 = (2 * wave + 0) * 16 + m;
  int col1 = col0 + 16;
  float bl0 = b_l[col0], bl1 = b_l[col1];
#pragma unroll
  for (int r = 0; r < 4; ++r) {
    long row0 = base + quad * 4 + r;
    long row1 = row0 + 16;
    out[row0 * C + col0] = fmaxf(acc0[r] + bl0, 0.0f);
    out[row0 * C + col1] = fmaxf(acc1[r] + bl1, 0.0f);
    out[row1 * C + col0] = fmaxf(acc2[r] + bl0, 0.0f);
    out[row1 * C + col1] = fmaxf(acc3[r] + bl1, 0.0f);
  }
}

extern "C" void kernel_launch(void* const* d_in, const int* in_sizes, int n_in,
                              void* d_out, int out_size, void* d_ws, size_t ws_size,
                              hipStream_t stream) {
  const float* x   = (const float*)d_in[0];
  const int* erow  = (const int*)d_in[1];   // dst
  const int* ecol  = (const int*)d_in[2];   // src
  const float* W_l = (const float*)d_in[3];
  const float* b_l = (const float*)d_in[4];
  const float* W_r = (const float*)d_in[5];
  float* out = (float*)d_out;

  char* p = (char*)d_ws;
  ushort* xh  = (ushort*)p;  p += (size_t)N_NODES * C * 2;      // 25.6 MB
  ushort* Bp  = (ushort*)p;  p += 2 * C * C * 2;                // 64 KB
  int* off    = (int*)p;     p += (size_t)(N_NODES + 4) * 4;    // 400 KB
  int* pairs  = (int*)p;     p += (size_t)NBKT * CAP * 4;       // 7.6 MB
  int* ssrc   = (int*)p;     p += (size_t)E_EDGES * 4;          // 6.4 MB
  int* bcnt   = (int*)p;

  hipMemsetAsync(bcnt, 0, NBKT * sizeof(int), stream);
  mega_kernel<<<PA_BLOCKS + PACK_BLOCKS + CVT_BLOCKS, 512, 0, stream>>>(
      x, erow, ecol, W_l, W_r, xh, Bp, bcnt, pairs);
  passB_kernel<<<NBKT, 1024, 0, stream>>>(pairs, bcnt, off, ssrc);
  fused_kernel<<<N_NODES / 32, 256, 0, stream>>>(xh, off, ssrc, Bp, b_l, out);
}